// Round 12
// baseline (213.699 us; speedup 1.0000x reference)
//
#include <hip/hip_runtime.h>
#include <math.h>

#define HIDDEN 4096
#define NEXP 64
#define TOPK 8
#define MARGIN 2.5e-4f
#define BK 64
#define TPB 64
#define NCHUNK (HIDDEN / BK)   // 64

using short8   = __attribute__((ext_vector_type(8))) short;   // 8 bf16 fragment
using floatx4  = __attribute__((ext_vector_type(4))) float;   // MFMA acc
using uint4v   = __attribute__((ext_vector_type(4))) unsigned int;

// d_ws: [0,4) redo counter | [64, 64+64K) redo list |
//       [128K, 640K) W'hi packed frags | [768K, 1280K) W'lo packed frags
#define WS_LIST_OFF (64)
#define WS_WHP_OFF  (128 * 1024)
#define WS_WLP_OFF  (768 * 1024)
#define WS_NEED     (1280 * 1024)

__device__ __forceinline__ unsigned short bf16_rn(float x) {
    unsigned int u = __builtin_bit_cast(unsigned int, x);
    unsigned int r = u + 0x7FFFu + ((u >> 16) & 1u);   // round-to-nearest-even
    return (unsigned short)(r >> 16);
}
__device__ __forceinline__ float bf16_to_f(unsigned short h) {
    unsigned int u = ((unsigned int)h) << 16;
    return __builtin_bit_cast(float, u);
}
__device__ __forceinline__ void gload16(const void* g, void* l) {
    __builtin_amdgcn_global_load_lds(
        (const __attribute__((address_space(1))) void*)g,
        (__attribute__((address_space(3))) void*)l, 16, 0, 0);
}

// ---- pass 0 (r11-proven): split W into bf16 hi/lo, pre-packed frag order.
// frag (c32, et), lane l, j: e = et*16+(l&15), k = c32*32+(l>>4)*8+j.
// packed ushort offset = ((c32*4 + et)*64 + l)*8 + j.
__global__ void wconv_kernel(const float* __restrict__ W,
                             unsigned short* __restrict__ Whp,
                             unsigned short* __restrict__ Wlp,
                             int* __restrict__ cnt) {
    if (blockIdx.x == 0 && threadIdx.x == 0) *cnt = 0;
    const int id  = blockIdx.x * 256 + threadIdx.x;    // 32768 total
    const int c32 = id >> 8;
    const int et  = (id >> 6) & 3;
    const int l   = id & 63;
    const int e   = et * 16 + (l & 15);
    const int k0  = c32 * 32 + (l >> 4) * 8;
    const float4 a = *reinterpret_cast<const float4*>(W + (size_t)e * HIDDEN + k0);
    const float4 b = *reinterpret_cast<const float4*>(W + (size_t)e * HIDDEN + k0 + 4);
    const float xs[8] = {a.x, a.y, a.z, a.w, b.x, b.y, b.z, b.w};
    short8 hv, lv;
#pragma unroll
    for (int j = 0; j < 8; ++j) {
        unsigned short h = bf16_rn(xs[j]);
        hv[j] = (short)h;
        lv[j] = (short)bf16_rn(xs[j] - bf16_to_f(h));
    }
    const size_t off = ((size_t)(c32 * 4 + et) * 64 + l) * 8;
    *reinterpret_cast<short8*>(Whp + off) = hv;
    *reinterpret_cast<short8*>(Wlp + off) = lv;
}

// ---- pass 1: MFMA gate. 512 thr = 8 waves; block = 64 tok x 64 exp.
// Wave w: expert tile et=w&3, K-half kh=w>>2. 4 token tiles (acc x4).
// X: LDS-staged 3 x 16KB (swizzled gload16, 2/wave/chunk, r11 skeleton).
// W': direct coalesced packed-frag loads, 2 KB/wave/chunk (hi+lo, own c32).
// Traffic: W' 268 MB + X 268 MB (was 1.07 GB + 268 MB at TPB=16).
__device__ __forceinline__ void convert(const float4& a, const float4& b,
                                        short8& ah, short8& al) {
    const unsigned int xu[8] = {
        __builtin_bit_cast(unsigned int, a.x), __builtin_bit_cast(unsigned int, a.y),
        __builtin_bit_cast(unsigned int, a.z), __builtin_bit_cast(unsigned int, a.w),
        __builtin_bit_cast(unsigned int, b.x), __builtin_bit_cast(unsigned int, b.y),
        __builtin_bit_cast(unsigned int, b.z), __builtin_bit_cast(unsigned int, b.w)};
    unsigned int hw[4], lw[4];
#pragma unroll
    for (int p = 0; p < 4; ++p) {
        unsigned int u0 = xu[2 * p], u1 = xu[2 * p + 1];
        hw[p] = __builtin_amdgcn_perm(u1, u0, 0x07060302u);   // hi16(u1):hi16(u0)
        float d0 = __builtin_bit_cast(float, u0) - __builtin_bit_cast(float, u0 & 0xFFFF0000u);
        float d1 = __builtin_bit_cast(float, u1) - __builtin_bit_cast(float, u1 & 0xFFFF0000u);
        lw[p] = __builtin_amdgcn_perm(__builtin_bit_cast(unsigned int, d1),
                                      __builtin_bit_cast(unsigned int, d0), 0x07060302u);
    }
    uint4v hv = {hw[0], hw[1], hw[2], hw[3]};
    uint4v lv = {lw[0], lw[1], lw[2], lw[3]};
    ah = __builtin_bit_cast(short8, hv);
    al = __builtin_bit_cast(short8, lv);
}

__global__ __launch_bounds__(512, 1)
void gate_mfma(const float* __restrict__ X,
               const unsigned short* __restrict__ Whp,
               const unsigned short* __restrict__ Wlp,
               float* __restrict__ out,
               int* __restrict__ redo_cnt, int* __restrict__ redo_list, int T) {
    __shared__ __align__(16) char smem[49152];   // 3 x 16KB X buffers
    const int tid  = threadIdx.x;
    const int lane = tid & 63;
    const int w    = tid >> 6;              // 0..7
    const int et   = w & 3;                 // expert tile
    const int kh   = w >> 2;                // K-half of each BK chunk
    const int t0   = blockIdx.x * TPB;

    // X staging: wave w stages rows 8w..8w+7 (2 gload16/chunk/wave).
    // LDS layout [64 rows][256 B], swizzle byte ^= (row&7)<<4 (rule 21).
    const int r0_  = w * 8 + (lane >> 4);          // rows 8w .. 8w+3
    const int r1_  = w * 8 + 4 + (lane >> 4);      // rows 8w+4 .. 8w+7
    const int sw0_ = ((lane & 15) * 16) ^ ((r0_ & 7) << 4);
    const int sw1_ = ((lane & 15) * 16) ^ ((r1_ & 7) << 4);
    const float* sg0 = X + (size_t)(t0 + r0_) * HIDDEN + (sw0_ >> 2);
    const float* sg1 = X + (size_t)(t0 + r1_) * HIDDEN + (sw1_ >> 2);
    auto STAGE = [&](int buf, int c) {
        gload16(sg0 + c * BK, smem + buf * 16384 + (w * 8) * 256);
        gload16(sg1 + c * BK, smem + buf * 16384 + (w * 8 + 4) * 256);
    };

    // packed W' base for (et, kh): chunk c -> c32 = 2c + kh
    const unsigned short* whb = Whp + (size_t)et * 512 + (size_t)lane * 8;
    const unsigned short* wlb = Wlp + (size_t)et * 512 + (size_t)lane * 8;
#define LOADW(WH, WL, c) do {                                                     \
    WH = *reinterpret_cast<const short8*>(whb + (size_t)(2 * (c) + kh) * 2048);   \
    WL = *reinterpret_cast<const short8*>(wlb + (size_t)(2 * (c) + kh) * 2048);   \
} while (0)

    floatx4 acc0 = {0.f,0.f,0.f,0.f}, acc1 = {0.f,0.f,0.f,0.f};
    floatx4 acc2 = {0.f,0.f,0.f,0.f}, acc3 = {0.f,0.f,0.f,0.f};

    // A-frag read addressing: tile a rows a*16+(lane&15); k-bytes kh*128 + (lane>>4)*32
    const int arow_in = lane & 15;
    const int akb     = kh * 128 + (lane >> 4) * 32;

#define COMPUTE(buf, WH, WL) do {                                                 \
    const char* xb_ = smem + (buf) * 16384;                                       \
    _Pragma("unroll")                                                             \
    for (int a_ = 0; a_ < 4; ++a_) {                                              \
        const int row_ = a_ * 16 + arow_in;                                       \
        const int swz_ = (row_ & 7) << 4;                                         \
        const float4 x0_ = *reinterpret_cast<const float4*>(                      \
            xb_ + row_ * 256 + ((akb) ^ swz_));                                   \
        const float4 x1_ = *reinterpret_cast<const float4*>(                      \
            xb_ + row_ * 256 + ((akb + 16) ^ swz_));                              \
        short8 ah_, al_;                                                          \
        convert(x0_, x1_, ah_, al_);                                              \
        floatx4& ac_ = (a_ == 0) ? acc0 : (a_ == 1) ? acc1 : (a_ == 2) ? acc2 : acc3; \
        ac_ = __builtin_amdgcn_mfma_f32_16x16x32_bf16(ah_, WH, ac_, 0, 0, 0);     \
        ac_ = __builtin_amdgcn_mfma_f32_16x16x32_bf16(ah_, WL, ac_, 0, 0, 0);     \
        ac_ = __builtin_amdgcn_mfma_f32_16x16x32_bf16(al_, WH, ac_, 0, 0, 0);     \
    }                                                                             \
} while (0)

    short8 whA, wlA, whB, wlB;

    // prologue: W(0); stage(0); stage(1); wait W(0)+S(0) (keep S(1) flying)
    LOADW(whA, wlA, 0);
    STAGE(0, 0);
    STAGE(1, 1);
    __builtin_amdgcn_sched_barrier(0);
    asm volatile("s_waitcnt vmcnt(2)\n\ts_barrier" ::: "memory");

#pragma unroll 1
    for (int c = 0; c < NCHUNK - 2; c += 2) {
        // H1: compute c (A), load W(c+1)->B, stage c+2
        LOADW(whB, wlB, c + 1);
        if (c + 2 < NCHUNK) STAGE((c + 2) % 3, c + 2);
        __builtin_amdgcn_sched_barrier(0);
        COMPUTE(c % 3, whA, wlA);
        asm volatile("s_waitcnt vmcnt(4)\n\ts_barrier" ::: "memory");
        // H2: compute c+1 (B), load W(c+2)->A, stage c+3
        LOADW(whA, wlA, c + 2);
        if (c + 3 < NCHUNK) STAGE((c + 3) % 3, c + 3);
        __builtin_amdgcn_sched_barrier(0);
        COMPUTE((c + 1) % 3, whB, wlB);
        asm volatile("s_waitcnt vmcnt(4)\n\ts_barrier" ::: "memory");
    }
    // tail: chunks 62 (A regs, staged), 63
    LOADW(whB, wlB, NCHUNK - 1);
    __builtin_amdgcn_sched_barrier(0);
    COMPUTE((NCHUNK - 2) % 3, whA, wlA);
    asm volatile("s_waitcnt vmcnt(0)\n\ts_barrier" ::: "memory");
    COMPUTE((NCHUNK - 1) % 3, whB, wlB);

    __syncthreads();
    // kh-reduce + assembly in LDS overlay [64][68].
    // D layout (verified r4-r11): col = lane&15 (expert), row = (lane>>4)*4+r
    float* accs = reinterpret_cast<float*>(smem);
    const int drw = (lane >> 4) * 4;
    const int dcl = et * 16 + (lane & 15);
    if (kh == 0) {
#pragma unroll
        for (int r = 0; r < 4; ++r) {
            accs[(     drw + r) * 68 + dcl] = acc0[r];
            accs[(16 + drw + r) * 68 + dcl] = acc1[r];
            accs[(32 + drw + r) * 68 + dcl] = acc2[r];
            accs[(48 + drw + r) * 68 + dcl] = acc3[r];
        }
    }
    __syncthreads();
    if (kh == 1) {
#pragma unroll
        for (int r = 0; r < 4; ++r) {
            accs[(     drw + r) * 68 + dcl] += acc0[r];
            accs[(16 + drw + r) * 68 + dcl] += acc1[r];
            accs[(32 + drw + r) * 68 + dcl] += acc2[r];
            accs[(48 + drw + r) * 68 + dcl] += acc3[r];
        }
    }
    __syncthreads();

    // epilogue: wave w handles token rows 8w..8w+7; lane = expert
    float* out_w = out;
    float* out_i = out + (size_t)T * TOPK;
#pragma unroll 1
    for (int m = 0; m < 8; ++m) {
        const int row = w * 8 + m;
        const int t = t0 + row;
        float lg = accs[row * 68 + lane];
        float v = 30.0f * tanhf(lg * (1.0f / 30.0f));
        float vcur = v, vmax0 = 0.f, my_e = 0.f, sum = 0.f, prev = 0.f;
        int   my_i = 0;
        bool  ambig = false;
#pragma unroll 1
        for (int k = 0; k < TOPK + 1; ++k) {   // ranks 1..9 with margin check
            float bv = vcur;
            int   bi = lane;
#pragma unroll
            for (int s = 32; s >= 1; s >>= 1) {
                float ov = __shfl_xor(bv, s);
                int   oi = __shfl_xor(bi, s);
                if (ov > bv || (ov == bv && oi < bi)) { bv = ov; bi = oi; }
            }
            if (k == 0) vmax0 = bv;
            else        ambig |= (prev - bv < MARGIN);
            prev = bv;
            if (k < TOPK) {
                float e = __expf(bv - vmax0);
                sum += e;
                if (lane == k) { my_e = e; my_i = bi; }
                if (lane == bi) vcur = -INFINITY;
            }
        }
        if (!ambig) {
            if (lane < TOPK) {
                out_w[(size_t)t * TOPK + lane] = my_e / sum;
                out_i[(size_t)t * TOPK + lane] = (float)my_i;
            }
        } else if (lane == 0) {
            redo_list[atomicAdd(redo_cnt, 1)] = t;
        }
    }
#undef LOADW
#undef COMPUTE
}

// ---- pass 2: exact f64 redo of ambiguous tokens ---------------------------
__global__ __launch_bounds__(256, 2)
void gate_redo(const float* __restrict__ X, const float* __restrict__ W,
               float* __restrict__ out,
               const int* __restrict__ redo_cnt, const int* __restrict__ redo_list,
               int T) {
    __shared__ double lgs[64];
    const int lane = threadIdx.x & 63;
    const int q    = threadIdx.x >> 6;
    const int n    = *redo_cnt;
    float* out_w = out;
    float* out_i = out + (size_t)T * TOPK;

    for (int i = blockIdx.x; i < n; i += gridDim.x) {
        const int t = redo_list[i];
        const float* xr = X + (size_t)t * HIDDEN;
#pragma unroll 1
        for (int j = 0; j < 16; ++j) {
            const int e = q * 16 + j;
            const float* wr = W + (size_t)e * HIDDEN;
            double s = 0.0;
#pragma unroll 2
            for (int k = lane * 4; k < HIDDEN; k += 256) {
                float4 wv = *reinterpret_cast<const float4*>(wr + k);
                float4 xv = *reinterpret_cast<const float4*>(xr + k);
                s = fma((double)xv.x, (double)wv.x, s);
                s = fma((double)xv.y, (double)wv.y, s);
                s = fma((double)xv.z, (double)wv.z, s);
                s = fma((double)xv.w, (double)wv.w, s);
            }
#pragma unroll
            for (int sft = 32; sft >= 1; sft >>= 1) s += __shfl_xor(s, sft);
            if (lane == 0) lgs[e] = s;
        }
        __syncthreads();
        if (q == 0) {
            double vv = 30.0 * tanh(lgs[lane] * (1.0 / 30.0));
            double dmax0 = 0.0, dmy_e = 0.0, dsum = 0.0;
            int    dmy_i = 0;
#pragma unroll 1
            for (int k = 0; k < TOPK; ++k) {
                double bv = vv;
                int    bi = lane;
#pragma unroll
                for (int s = 32; s >= 1; s >>= 1) {
                    double ov = __shfl_xor(bv, s);
                    int    oi = __shfl_xor(bi, s);
                    if (ov > bv || (ov == bv && oi < bi)) { bv = ov; bi = oi; }
                }
                if (k == 0) dmax0 = bv;
                double e = exp(bv - dmax0);
                dsum += e;
                if (lane == k) { dmy_e = e; dmy_i = bi; }
                if (lane == bi) vv = -HUGE_VAL;
            }
            if (lane < TOPK) {
                out_w[(size_t)t * TOPK + lane] = (float)(dmy_e / dsum);
                out_i[(size_t)t * TOPK + lane] = (float)dmy_i;
            }
        }
        __syncthreads();
    }
}

// ---- fallback (round-3 proven) if ws too small ----------------------------
#define F_HC 64
#define F_LDS_STRIDE 68
#define F_TPW 4
#define F_TPB 16

__global__ __launch_bounds__(256, 4)
void moe_gate_fallback(const float* __restrict__ X, const float* __restrict__ W,
                       float* __restrict__ out, int T) {
    __shared__ float wlds[NEXP * F_LDS_STRIDE];
    const int tid  = threadIdx.x;
    const int lane = tid & 63;
    const int wid  = tid >> 6;
    const int t0   = blockIdx.x * F_TPB + wid * F_TPW;
    double accd[F_TPW];
#pragma unroll
    for (int m = 0; m < F_TPW; ++m) accd[m] = 0.0;
    for (int hb = 0; hb < HIDDEN; hb += F_HC) {
        __syncthreads();
#pragma unroll
        for (int k = 0; k < 4; ++k) {
            int f = tid + k * 256, e = f >> 4, c4 = f & 15;
            const float4 wv = *reinterpret_cast<const float4*>(W + e * HIDDEN + hb + c4 * 4);
            *reinterpret_cast<float4*>(&wlds[e * F_LDS_STRIDE + c4 * 4]) = wv;
        }
        __syncthreads();
        float accf[F_TPW];
#pragma unroll
        for (int m = 0; m < F_TPW; ++m) accf[m] = 0.f;
#pragma unroll 4
        for (int h4 = 0; h4 < F_HC / 4; ++h4) {
            const float4 wv = *reinterpret_cast<const float4*>(&wlds[lane * F_LDS_STRIDE + h4 * 4]);
#pragma unroll
            for (int m = 0; m < F_TPW; ++m) {
                const float4 xv = *reinterpret_cast<const float4*>(
                    X + (size_t)(t0 + m) * HIDDEN + hb + h4 * 4);
                accf[m] = fmaf(xv.x, wv.x, accf[m]);
                accf[m] = fmaf(xv.y, wv.y, accf[m]);
                accf[m] = fmaf(xv.z, wv.z, accf[m]);
                accf[m] = fmaf(xv.w, wv.w, accf[m]);
            }
        }
#pragma unroll
        for (int m = 0; m < F_TPW; ++m) accd[m] += (double)accf[m];
    }
    float* out_w = out;
    float* out_i = out + (size_t)T * TOPK;
#pragma unroll 1
    for (int m = 0; m < F_TPW; ++m) {
        const int t = t0 + m;
        double vv = 30.0 * tanh(accd[m] * (1.0 / 30.0));
        double dmax0 = 0.0, dmy_e = 0.0, dsum = 0.0;
        int dmy_i = 0;
#pragma unroll 1
        for (int k = 0; k < TOPK; ++k) {
            double bv = vv; int bi = lane;
#pragma unroll
            for (int s = 32; s >= 1; s >>= 1) {
                double ov = __shfl_xor(bv, s);
                int    oi = __shfl_xor(bi, s);
                if (ov > bv || (ov == bv && oi < bi)) { bv = ov; bi = oi; }
            }
            if (k == 0) dmax0 = bv;
            double e = exp(bv - dmax0);
            dsum += e;
            if (lane == k) { dmy_e = e; dmy_i = bi; }
            if (lane == bi) vv = -HUGE_VAL;
        }
        if (lane < TOPK) {
            out_w[(size_t)t * TOPK + lane] = (float)(dmy_e / dsum);
            out_i[(size_t)t * TOPK + lane] = (float)dmy_i;
        }
    }
}

extern "C" void kernel_launch(void* const* d_in, const int* in_sizes, int n_in,
                              void* d_out, int out_size, void* d_ws, size_t ws_size,
                              hipStream_t stream) {
    const float* X = (const float*)d_in[0];     // [4,4096,4096] fp32
    const float* W = (const float*)d_in[1];     // [64,4096] fp32
    float* out = (float*)d_out;
    const int T = in_sizes[0] / HIDDEN;         // 16384

    if (ws_size < WS_NEED) {
        hipLaunchKernelGGL(moe_gate_fallback, dim3(T / F_TPB), dim3(256), 0, stream, X, W, out, T);
        return;
    }
    char* ws = (char*)d_ws;
    int* cnt  = (int*)ws;
    int* list = (int*)(ws + WS_LIST_OFF);
    unsigned short* Whp = (unsigned short*)(ws + WS_WHP_OFF);
    unsigned short* Wlp = (unsigned short*)(ws + WS_WLP_OFF);

    hipLaunchKernelGGL(wconv_kernel, dim3(128), dim3(256), 0, stream, W, Whp, Wlp, cnt);
    hipLaunchKernelGGL(gate_mfma, dim3(T / TPB), dim3(512), 0, stream,
                       X, Whp, Wlp, out, cnt, list, T);
    hipLaunchKernelGGL(gate_redo, dim3(256), dim3(256), 0, stream,
                       X, W, out, cnt, list, T);
}

// Round 14
// 210.690 us; speedup vs baseline: 1.0143x; 1.0143x over previous
//
#include <hip/hip_runtime.h>
#include <math.h>

#define HIDDEN 4096
#define NEXP 64
#define TOPK 8
#define MARGIN 2.5e-4f
#define BK 256            // k-elements per chunk (1 KB per X row visit)
#define TPB 16
#define NCHUNK (HIDDEN / BK)   // 16

using short8   = __attribute__((ext_vector_type(8))) short;   // 8 bf16 fragment
using floatx4  = __attribute__((ext_vector_type(4))) float;   // MFMA acc
using uint4v   = __attribute__((ext_vector_type(4))) unsigned int;

// d_ws: [0,4) redo counter | [64, 64+64K) redo list |
//       [128K, 640K) W'hi packed frags | [768K, 1280K) W'lo packed frags
#define WS_LIST_OFF (64)
#define WS_WHP_OFF  (128 * 1024)
#define WS_WLP_OFF  (768 * 1024)
#define WS_NEED     (1280 * 1024)

__device__ __forceinline__ unsigned short bf16_rn(float x) {
    unsigned int u = __builtin_bit_cast(unsigned int, x);
    unsigned int r = u + 0x7FFFu + ((u >> 16) & 1u);   // round-to-nearest-even
    return (unsigned short)(r >> 16);
}
__device__ __forceinline__ float bf16_to_f(unsigned short h) {
    unsigned int u = ((unsigned int)h) << 16;
    return __builtin_bit_cast(float, u);
}
__device__ __forceinline__ void gload16(const void* g, void* l) {
    __builtin_amdgcn_global_load_lds(
        (const __attribute__((address_space(1))) void*)g,
        (__attribute__((address_space(3))) void*)l, 16, 0, 0);
}

// ---- pass 0 (r11-proven, unchanged): W -> bf16 hi/lo packed frag order.
// frag (c32, et), lane l, j: e = et*16+(l&15), k = c32*32+(l>>4)*8+j.
// packed ushort offset = ((c32*4 + et)*64 + l)*8 + j.
__global__ void wconv_kernel(const float* __restrict__ W,
                             unsigned short* __restrict__ Whp,
                             unsigned short* __restrict__ Wlp,
                             int* __restrict__ cnt) {
    if (blockIdx.x == 0 && threadIdx.x == 0) *cnt = 0;
    const int id  = blockIdx.x * 256 + threadIdx.x;    // 32768 total
    const int c32 = id >> 8;
    const int et  = (id >> 6) & 3;
    const int l   = id & 63;
    const int e   = et * 16 + (l & 15);
    const int k0  = c32 * 32 + (l >> 4) * 8;
    const float4 a = *reinterpret_cast<const float4*>(W + (size_t)e * HIDDEN + k0);
    const float4 b = *reinterpret_cast<const float4*>(W + (size_t)e * HIDDEN + k0 + 4);
    const float xs[8] = {a.x, a.y, a.z, a.w, b.x, b.y, b.z, b.w};
    short8 hv, lv;
#pragma unroll
    for (int j = 0; j < 8; ++j) {
        unsigned short h = bf16_rn(xs[j]);
        hv[j] = (short)h;
        lv[j] = (short)bf16_rn(xs[j] - bf16_to_f(h));
    }
    const size_t off = ((size_t)(c32 * 4 + et) * 64 + l) * 8;
    *reinterpret_cast<short8*>(Whp + off) = hv;
    *reinterpret_cast<short8*>(Wlp + off) = lv;
}

// ---- pass 1: MFMA gate, BK=256. 256 thr = 4 waves; block = 16 tok x 64 exp.
// Wave q = expert tile. X: LDS 3 x 16KB, rows of 1 KB (one gload16 covers a
// full row), pre-swizzled source (rule 21), byte ^= (row&7)<<4 on read.
// W': direct packed-frag loads (L2-resident), double-buffered per half-chunk
// in named reg arrays (static unroll, rule 20). Raw s_barrier per chunk —
// stage(c+1) is drained by each wave's younger W-reg dep wait before it, so
// stage(c+2)+LOADW(c+1) stay in flight across the barrier (no vmcnt(0)).
__device__ __forceinline__ void convert(const float4& a, const float4& b,
                                        short8& ah, short8& al) {
    const unsigned int xu[8] = {
        __builtin_bit_cast(unsigned int, a.x), __builtin_bit_cast(unsigned int, a.y),
        __builtin_bit_cast(unsigned int, a.z), __builtin_bit_cast(unsigned int, a.w),
        __builtin_bit_cast(unsigned int, b.x), __builtin_bit_cast(unsigned int, b.y),
        __builtin_bit_cast(unsigned int, b.z), __builtin_bit_cast(unsigned int, b.w)};
    unsigned int hw[4], lw[4];
#pragma unroll
    for (int p = 0; p < 4; ++p) {
        unsigned int u0 = xu[2 * p], u1 = xu[2 * p + 1];
        hw[p] = __builtin_amdgcn_perm(u1, u0, 0x07060302u);   // hi16(u1):hi16(u0)
        float d0 = __builtin_bit_cast(float, u0) - __builtin_bit_cast(float, u0 & 0xFFFF0000u);
        float d1 = __builtin_bit_cast(float, u1) - __builtin_bit_cast(float, u1 & 0xFFFF0000u);
        lw[p] = __builtin_amdgcn_perm(__builtin_bit_cast(unsigned int, d1),
                                      __builtin_bit_cast(unsigned int, d0), 0x07060302u);
    }
    uint4v hv = {hw[0], hw[1], hw[2], hw[3]};
    uint4v lv = {lw[0], lw[1], lw[2], lw[3]};
    ah = __builtin_bit_cast(short8, hv);
    al = __builtin_bit_cast(short8, lv);
}

__global__ __launch_bounds__(256, 4)
void gate_mfma(const float* __restrict__ X,
               const unsigned short* __restrict__ Whp,
               const unsigned short* __restrict__ Wlp,
               float* __restrict__ out,
               int* __restrict__ redo_cnt, int* __restrict__ redo_list, int T) {
    __shared__ __align__(16) char smem[49152];   // 3 x 16KB X buffers
    const int tid  = threadIdx.x;
    const int lane = tid & 63;
    const int q    = tid >> 6;              // 0..3 = expert tile
    const int t0   = blockIdx.x * TPB;

    // X staging: wave q stages rows 4q..4q+3; one gload16 covers a 1KB row.
    auto STAGE = [&](int buf, int c) {
#pragma unroll
        for (int r = 0; r < 4; ++r) {
            const int row = q * 4 + r;
            const int sw  = (lane * 16) ^ ((row & 7) << 4);   // inverse-swz src
            gload16(X + (size_t)(t0 + row) * HIDDEN + c * BK + (sw >> 2),
                    smem + buf * 16384 + row * 1024);
        }
    };

    // packed W' base for et=q; c32 = 8c + 4h + s
    const unsigned short* whb = Whp + (size_t)q * 512 + (size_t)lane * 8;
    const unsigned short* wlb = Wlp + (size_t)q * 512 + (size_t)lane * 8;

#define LOADW(WH, WL, c, h) do {                                                  \
    _Pragma("unroll")                                                             \
    for (int s_ = 0; s_ < 4; ++s_) {                                              \
        WH[s_] = *reinterpret_cast<const short8*>(                                \
            whb + (size_t)(8 * (c) + 4 * (h) + s_) * 2048);                       \
        WL[s_] = *reinterpret_cast<const short8*>(                                \
            wlb + (size_t)(8 * (c) + 4 * (h) + s_) * 2048);                       \
    }                                                                             \
} while (0)

    floatx4 acc = {0.f, 0.f, 0.f, 0.f};
    const int arow = lane & 15;
    const int aswz = (arow & 7) << 4;
    const int klo  = (lane >> 4) * 32;      // byte offset of lane's k-slice

#define COMPUTE_HALF(buf, h, WH, WL) do {                                         \
    const char* xb_ = smem + (buf) * 16384 + arow * 1024;                         \
    _Pragma("unroll")                                                             \
    for (int s_ = 0; s_ < 4; ++s_) {                                              \
        const int kb_ = ((h) * 4 + s_) * 128 + klo;                               \
        const float4 x0_ = *reinterpret_cast<const float4*>(xb_ + ((kb_) ^ aswz));\
        const float4 x1_ = *reinterpret_cast<const float4*>(xb_ + ((kb_ + 16) ^ aswz)); \
        short8 ah_, al_;                                                          \
        convert(x0_, x1_, ah_, al_);                                              \
        acc = __builtin_amdgcn_mfma_f32_16x16x32_bf16(ah_, WH[s_], acc, 0, 0, 0); \
        acc = __builtin_amdgcn_mfma_f32_16x16x32_bf16(ah_, WL[s_], acc, 0, 0, 0); \
        acc = __builtin_amdgcn_mfma_f32_16x16x32_bf16(al_, WH[s_], acc, 0, 0, 0); \
    }                                                                             \
} while (0)

    short8 whA[4], wlA[4], whB[4], wlB[4];

    // prologue: W(0,h0)[8]; stage(0)[4]; stage(1)[4]; wait W+S0 (keep S1)
    LOADW(whA, wlA, 0, 0);
    STAGE(0, 0);
    STAGE(1, 1);
    __builtin_amdgcn_sched_barrier(0);
    asm volatile("s_waitcnt vmcnt(4)" ::: "memory");
    __builtin_amdgcn_s_barrier();
    __builtin_amdgcn_sched_barrier(0);

#pragma unroll 1
    for (int c = 0; c < NCHUNK - 1; ++c) {
        LOADW(whB, wlB, c, 1);                       // half-2 W regs
        if (c + 2 < NCHUNK) STAGE((c + 2) % 3, c + 2);
        __builtin_amdgcn_sched_barrier(0);
        COMPUTE_HALF(c % 3, 0, whA, wlA);
        LOADW(whA, wlA, c + 1, 0);                   // next chunk half-1
        __builtin_amdgcn_sched_barrier(0);
        COMPUTE_HALF(c % 3, 1, whB, wlB);            // reg-dep wait drains S(c+1)
        __builtin_amdgcn_sched_barrier(0);
        __builtin_amdgcn_s_barrier();                // raw: no vmcnt(0) drain
        __builtin_amdgcn_sched_barrier(0);
    }
    // tail chunk 15
    LOADW(whB, wlB, NCHUNK - 1, 1);
    __builtin_amdgcn_sched_barrier(0);
    COMPUTE_HALF((NCHUNK - 1) % 3, 0, whA, wlA);
    COMPUTE_HALF((NCHUNK - 1) % 3, 1, whB, wlB);

    __syncthreads();   // full drain once before LDS overlay
    // D layout (verified r4-r12): col = lane&15 (expert), row = (lane>>4)*4+r
    float* accs = reinterpret_cast<float*>(smem);   // [16][68] overlay
    const int drow = (lane >> 4) * 4;
    const int dcol = q * 16 + (lane & 15);
#pragma unroll
    for (int r = 0; r < 4; ++r) accs[(drow + r) * 68 + dcol] = acc[r];
    __syncthreads();

    // epilogue (r11-proven): wave q rows 4q..4q+3; lane = expert
    float* out_w = out;
    float* out_i = out + (size_t)T * TOPK;
#pragma unroll 1
    for (int m = 0; m < 4; ++m) {
        const int row = q * 4 + m;
        const int t = t0 + row;
        float lg = accs[row * 68 + lane];
        float v = 30.0f * tanhf(lg * (1.0f / 30.0f));
        float vcur = v, vmax0 = 0.f, my_e = 0.f, sum = 0.f, prev = 0.f;
        int   my_i = 0;
        bool  ambig = false;
#pragma unroll 1
        for (int k = 0; k < TOPK + 1; ++k) {   // ranks 1..9 with margin check
            float bv = vcur;
            int   bi = lane;
#pragma unroll
            for (int s = 32; s >= 1; s >>= 1) {
                float ov = __shfl_xor(bv, s);
                int   oi = __shfl_xor(bi, s);
                if (ov > bv || (ov == bv && oi < bi)) { bv = ov; bi = oi; }
            }
            if (k == 0) vmax0 = bv;
            else        ambig |= (prev - bv < MARGIN);
            prev = bv;
            if (k < TOPK) {
                float e = __expf(bv - vmax0);
                sum += e;
                if (lane == k) { my_e = e; my_i = bi; }
                if (lane == bi) vcur = -INFINITY;
            }
        }
        if (!ambig) {
            if (lane < TOPK) {
                out_w[(size_t)t * TOPK + lane] = my_e / sum;
                out_i[(size_t)t * TOPK + lane] = (float)my_i;
            }
        } else if (lane == 0) {
            redo_list[atomicAdd(redo_cnt, 1)] = t;
        }
    }
#undef LOADW
#undef COMPUTE_HALF
}

// ---- pass 2: exact f64 redo of ambiguous tokens (proven, unchanged) -------
__global__ __launch_bounds__(256, 2)
void gate_redo(const float* __restrict__ X, const float* __restrict__ W,
               float* __restrict__ out,
               const int* __restrict__ redo_cnt, const int* __restrict__ redo_list,
               int T) {
    __shared__ double lgs[64];
    const int lane = threadIdx.x & 63;
    const int q    = threadIdx.x >> 6;
    const int n    = *redo_cnt;
    float* out_w = out;
    float* out_i = out + (size_t)T * TOPK;

    for (int i = blockIdx.x; i < n; i += gridDim.x) {
        const int t = redo_list[i];
        const float* xr = X + (size_t)t * HIDDEN;
#pragma unroll 1
        for (int j = 0; j < 16; ++j) {
            const int e = q * 16 + j;
            const float* wr = W + (size_t)e * HIDDEN;
            double s = 0.0;
#pragma unroll 2
            for (int k = lane * 4; k < HIDDEN; k += 256) {
                float4 wv = *reinterpret_cast<const float4*>(wr + k);
                float4 xv = *reinterpret_cast<const float4*>(xr + k);
                s = fma((double)xv.x, (double)wv.x, s);
                s = fma((double)xv.y, (double)wv.y, s);
                s = fma((double)xv.z, (double)wv.z, s);
                s = fma((double)xv.w, (double)wv.w, s);
            }
#pragma unroll
            for (int sft = 32; sft >= 1; sft >>= 1) s += __shfl_xor(s, sft);
            if (lane == 0) lgs[e] = s;
        }
        __syncthreads();
        if (q == 0) {
            double vv = 30.0 * tanh(lgs[lane] * (1.0 / 30.0));
            double dmax0 = 0.0, dmy_e = 0.0, dsum = 0.0;
            int    dmy_i = 0;
#pragma unroll 1
            for (int k = 0; k < TOPK; ++k) {
                double bv = vv;
                int    bi = lane;
#pragma unroll
                for (int s = 32; s >= 1; s >>= 1) {
                    double ov = __shfl_xor(bv, s);
                    int    oi = __shfl_xor(bi, s);
                    if (ov > bv || (ov == bv && oi < bi)) { bv = ov; bi = oi; }
                }
                if (k == 0) dmax0 = bv;
                double e = exp(bv - dmax0);
                dsum += e;
                if (lane == k) { dmy_e = e; dmy_i = bi; }
                if (lane == bi) vv = -HUGE_VAL;
            }
            if (lane < TOPK) {
                out_w[(size_t)t * TOPK + lane] = (float)(dmy_e / dsum);
                out_i[(size_t)t * TOPK + lane] = (float)dmy_i;
            }
        }
        __syncthreads();
    }
}

// ---- fallback (round-3 proven) if ws too small ----------------------------
#define F_HC 64
#define F_LDS_STRIDE 68
#define F_TPW 4
#define F_TPB 16

__global__ __launch_bounds__(256, 4)
void moe_gate_fallback(const float* __restrict__ X, const float* __restrict__ W,
                       float* __restrict__ out, int T) {
    __shared__ float wlds[NEXP * F_LDS_STRIDE];
    const int tid  = threadIdx.x;
    const int lane = tid & 63;
    const int wid  = tid >> 6;
    const int t0   = blockIdx.x * F_TPB + wid * F_TPW;
    double accd[F_TPW];
#pragma unroll
    for (int m = 0; m < F_TPW; ++m) accd[m] = 0.0;
    for (int hb = 0; hb < HIDDEN; hb += F_HC) {
        __syncthreads();
#pragma unroll
        for (int k = 0; k < 4; ++k) {
            int f = tid + k * 256, e = f >> 4, c4 = f & 15;
            const float4 wv = *reinterpret_cast<const float4*>(W + e * HIDDEN + hb + c4 * 4);
            *reinterpret_cast<float4*>(&wlds[e * F_LDS_STRIDE + c4 * 4]) = wv;
        }
        __syncthreads();
        float accf[F_TPW];
#pragma unroll
        for (int m = 0; m < F_TPW; ++m) accf[m] = 0.f;
#pragma unroll 4
        for (int h4 = 0; h4 < F_HC / 4; ++h4) {
            const float4 wv = *reinterpret_cast<const float4*>(&wlds[lane * F_LDS_STRIDE + h4 * 4]);
#pragma unroll
            for (int m = 0; m < F_TPW; ++m) {
                const float4 xv = *reinterpret_cast<const float4*>(
                    X + (size_t)(t0 + m) * HIDDEN + hb + h4 * 4);
                accf[m] = fmaf(xv.x, wv.x, accf[m]);
                accf[m] = fmaf(xv.y, wv.y, accf[m]);
                accf[m] = fmaf(xv.z, wv.z, accf[m]);
                accf[m] = fmaf(xv.w, wv.w, accf[m]);
            }
        }
#pragma unroll
        for (int m = 0; m < F_TPW; ++m) accd[m] += (double)accf[m];
    }
    float* out_w = out;
    float* out_i = out + (size_t)T * TOPK;
#pragma unroll 1
    for (int m = 0; m < F_TPW; ++m) {
        const int t = t0 + m;
        double vv = 30.0 * tanh(accd[m] * (1.0 / 30.0));
        double dmax0 = 0.0, dmy_e = 0.0, dsum = 0.0;
        int dmy_i = 0;
#pragma unroll 1
        for (int k = 0; k < TOPK; ++k) {
            double bv = vv; int bi = lane;
#pragma unroll
            for (int s = 32; s >= 1; s >>= 1) {
                double ov = __shfl_xor(bv, s);
                int    oi = __shfl_xor(bi, s);
                if (ov > bv || (ov == bv && oi < bi)) { bv = ov; bi = oi; }
            }
            if (k == 0) dmax0 = bv;
            double e = exp(bv - dmax0);
            dsum += e;
            if (lane == k) { dmy_e = e; dmy_i = bi; }
            if (lane == bi) vv = -HUGE_VAL;
        }
        if (lane < TOPK) {
            out_w[(size_t)t * TOPK + lane] = (float)(dmy_e / dsum);
            out_i[(size_t)t * TOPK + lane] = (float)dmy_i;
        }
    }
}

extern "C" void kernel_launch(void* const* d_in, const int* in_sizes, int n_in,
                              void* d_out, int out_size, void* d_ws, size_t ws_size,
                              hipStream_t stream) {
    const float* X = (const float*)d_in[0];     // [4,4096,4096] fp32
    const float* W = (const float*)d_in[1];     // [64,4096] fp32
    float* out = (float*)d_out;
    const int T = in_sizes[0] / HIDDEN;         // 16384

    if (ws_size < WS_NEED) {
        hipLaunchKernelGGL(moe_gate_fallback, dim3(T / F_TPB), dim3(256), 0, stream, X, W, out, T);
        return;
    }
    char* ws = (char*)d_ws;
    int* cnt  = (int*)ws;
    int* list = (int*)(ws + WS_LIST_OFF);
    unsigned short* Whp = (unsigned short*)(ws + WS_WHP_OFF);
    unsigned short* Wlp = (unsigned short*)(ws + WS_WLP_OFF);

    hipLaunchKernelGGL(wconv_kernel, dim3(128), dim3(256), 0, stream, W, Whp, Wlp, cnt);
    hipLaunchKernelGGL(gate_mfma, dim3(T / TPB), dim3(256), 0, stream,
                       X, Whp, Wlp, out, cnt, list, T);
    hipLaunchKernelGGL(gate_redo, dim3(256), dim3(256), 0, stream,
                       X, W, out, cnt, list, T);
}